// Round 8
// baseline (456.816 us; speedup 1.0000x reference)
//
#include <hip/hip_runtime.h>
#include <hip/hip_bf16.h>

// Channel attention (4 heads, dilated 3x3 key convs d=1,2,4,8), f16 MFMA pipeline.
// R8: convk -- single-buffer 46KB LDS (halo+weights staged together) -> 3 blocks/CU,
// 3 waves/SIMD; TLP hides staging latency instead of double-buffering.
//
// ws layout (bytes):
//   kbuf : [0,           67108864)   k  f16 [h][b][p][n]
//   vT   : [67108864,   134217728)   v  f16 [h][b][n][p]   (pixel-major)
//   attn : [134217728,  134479872)   attn f16 [h][b][o][p]
//   Wqv  : [134479872,  134742016)   f16 (512x256)
//   Wkb  : [134742016,  135921664)   f16 [h][t][ks32][p64][8]  (MFMA A-frag native)
//   zpage: [135921664,  135921920)   zeros (OOB load source)
// d_out reused as scratch (dead before final kernel):
//   xT   : bytes [0, 64Mi)   f16 [b][n][c]
//   q    : bytes [64Mi,128Mi) f16 [h][b][o][n]
//   part : bytes [0, 4Mi)    fp32 partial scores (written AFTER conv, xT dead)

typedef __attribute__((ext_vector_type(8))) _Float16 f16x8;
typedef __attribute__((ext_vector_type(4))) float f32x4;
typedef __attribute__((ext_vector_type(16))) float f32x16;

__device__ __forceinline__ unsigned short f2h(float f) {
  union { _Float16 h; unsigned short u; } v;
  v.h = (_Float16)f;
  return v.u;
}

__device__ __forceinline__ f32x4 mfma16(f16x8 a, f16x8 b, f32x4 c) {
  return __builtin_amdgcn_mfma_f32_16x16x32_f16(a, b, c, 0, 0, 0);
}
__device__ __forceinline__ f32x16 mfma32(f16x8 a, f16x8 b, f32x16 c) {
  return __builtin_amdgcn_mfma_f32_32x32x16_f16(a, b, c, 0, 0, 0);
}

// swizzled index into a [R][64]-ushort tile (128B rows): XOR bits 4..6 of byte off
__device__ __forceinline__ int sw(int row, int c) {
  return row * 64 + ((((c << 1) ^ ((row & 7) << 4)) >> 1));
}

// ---------------- weight prep ----------------
__global__ __launch_bounds__(256) void prep(const float* __restrict__ Wq,
                                            const float* __restrict__ Wv,
                                            const float* __restrict__ Wk,
                                            unsigned short* __restrict__ Wqv,
                                            unsigned short* __restrict__ Wkb,
                                            unsigned short* __restrict__ zp) {
  int i = blockIdx.x * 256 + threadIdx.x;
  if (blockIdx.x == 0 && threadIdx.x < 128) zp[threadIdx.x] = 0;
  const int total = 131072 + 589824;
  if (i >= total) return;
  if (i < 131072) {
    Wqv[i] = f2h(i < 65536 ? Wq[i] : Wv[i - 65536]);
  } else {
    int j = i - 131072;  // (((h*9+t)*32 + ks)*64 + p)*8 + jj
    int jj = j & 7;
    int p = (j >> 3) & 63;
    int ks = (j >> 9) & 31;
    int ht = j >> 14;
    int t = ht % 9;
    int h = ht / 9;
    Wkb[j] = f2h(Wk[(size_t)((h * 64 + p) * 256 + ks * 8 + jj) * 9 + t]);
  }
}

// ---------------- x (b,c,n) fp32 -> xT (b,n,c) f16 ----------------
__global__ __launch_bounds__(256) void xpose(const float* __restrict__ x,
                                             unsigned short* __restrict__ xT) {
  __shared__ unsigned short tile[64][66];
  int n0 = blockIdx.x * 64, c0 = blockIdx.y * 64, b = blockIdx.z;
  int t = threadIdx.x;
  int r = t >> 2, q = t & 3;
  const float* src = x + (size_t)b * 4194304 + (size_t)(c0 + r) * 16384 + n0 + q * 16;
#pragma unroll
  for (int i = 0; i < 4; i++) {
    float4 v = *(const float4*)(src + i * 4);
    tile[r][q * 16 + i * 4 + 0] = f2h(v.x);
    tile[r][q * 16 + i * 4 + 1] = f2h(v.y);
    tile[r][q * 16 + i * 4 + 2] = f2h(v.z);
    tile[r][q * 16 + i * 4 + 3] = f2h(v.w);
  }
  __syncthreads();
  int c = t & 63, pq = t >> 6;
  unsigned short* dst = xT + (size_t)b * 4194304 + (size_t)n0 * 256 + c0 + c;
#pragma unroll
  for (int i = 0; i < 16; i++) {
    int px = i * 4 + pq;
    dst[(size_t)px * 256] = tile[c][px];
  }
}

// ---------------- Q/V projection: q-tile + v-tile paired, shared x staging -----
__global__ __launch_bounds__(256) void proj(const unsigned short* __restrict__ xT,
                                            const unsigned short* __restrict__ Wqv,
                                            const float* __restrict__ bq,
                                            const float* __restrict__ bv,
                                            unsigned short* __restrict__ qout,
                                            unsigned short* __restrict__ vT) {
  __shared__ __align__(16) unsigned short As[2][64 * 64];
  __shared__ __align__(16) unsigned short Bs[256 * 64];
  int n0 = blockIdx.x * 256, y = blockIdx.y, b = blockIdx.z;
  int h = y;  // head
  int tid = threadIdx.x, lane = tid & 63, w = tid >> 6;
  int l15 = lane & 15, uq = lane >> 4;
  const f32x4 fz = {0.f, 0.f, 0.f, 0.f};
  f32x4 acc[2][4][4];
#pragma unroll
  for (int m = 0; m < 2; m++)
#pragma unroll
    for (int i = 0; i < 4; i++)
#pragma unroll
      for (int j = 0; j < 4; j++) acc[m][i][j] = fz;

  const unsigned short* xb = xT + (size_t)b * 4194304;
  for (int k0 = 0; k0 < 256; k0 += 64) {
    __syncthreads();
    for (int p = tid; p < 1024; p += 256) {
      int sel = p >> 9, row = (p >> 3) & 63, j = p & 7;
      int m0 = sel * 256 + y * 64;
      uint4 v = *(const uint4*)(Wqv + (size_t)(m0 + row) * 256 + k0 + j * 8);
      *(uint4*)&As[sel][sw(row, j * 8)] = v;
    }
    for (int p = tid; p < 2048; p += 256) {
      int px = p >> 3, j = p & 7;
      uint4 v = *(const uint4*)(xb + (size_t)(n0 + px) * 256 + k0 + j * 8);
      *(uint4*)&Bs[sw(px, j * 8)] = v;
    }
    __syncthreads();
#pragma unroll
    for (int kk = 0; kk < 2; kk++) {
      f16x8 bfr[4];
#pragma unroll
      for (int nf = 0; nf < 4; nf++)
        bfr[nf] = *(const f16x8*)&Bs[sw(w * 64 + nf * 16 + l15, kk * 32 + uq * 8)];
#pragma unroll
      for (int mh = 0; mh < 2; mh++)
#pragma unroll
        for (int mf = 0; mf < 4; mf++) {
          f16x8 afr = *(const f16x8*)&As[mh][sw(mf * 16 + l15, kk * 32 + uq * 8)];
#pragma unroll
          for (int nf = 0; nf < 4; nf++)
            acc[mh][mf][nf] = mfma16(afr, bfr[nf], acc[mh][mf][nf]);
        }
    }
  }
  // q path (mh=0)
  {
    unsigned short* qb = qout + (size_t)((h * 8 + b) * 64) * 16384;
#pragma unroll
    for (int mf = 0; mf < 4; mf++)
#pragma unroll
      for (int nf = 0; nf < 4; nf++) {
        int n = n0 + w * 64 + nf * 16 + l15;
#pragma unroll
        for (int r = 0; r < 4; r++) {
          int o = mf * 16 + 4 * uq + r;
          qb[(size_t)o * 16384 + n] = f2h(acc[0][mf][nf][r] + bq[h * 64 + o]);
        }
      }
  }
  // v path (mh=1)
  {
    unsigned short* vb = vT + (size_t)(h * 8 + b) * 16384 * 64;
#pragma unroll
    for (int mf = 0; mf < 4; mf++) {
      int p0 = mf * 16 + 4 * uq;
#pragma unroll
      for (int nf = 0; nf < 4; nf++) {
        int n = n0 + w * 64 + nf * 16 + l15;
        unsigned short t0 = f2h(acc[1][mf][nf][0] + bv[h * 64 + p0 + 0]);
        unsigned short t1 = f2h(acc[1][mf][nf][1] + bv[h * 64 + p0 + 1]);
        unsigned short t2 = f2h(acc[1][mf][nf][2] + bv[h * 64 + p0 + 2]);
        unsigned short t3 = f2h(acc[1][mf][nf][3] + bv[h * 64 + p0 + 3]);
        uint2 pk;
        pk.x = (unsigned)t0 | ((unsigned)t1 << 16);
        pk.y = (unsigned)t2 | ((unsigned)t3 << 16);
        *(uint2*)&vb[(size_t)n * 64 + p0] = pk;
      }
    }
  }
}

// ---------------- dilated 3x3 conv (keys): 4 d-spaced rows, all-LDS operands ---
// Single 46KB buffer -> 3 blocks/CU (3 waves/SIMD). Per chunk:
// [STAGE issue; vmcnt(0); barrier; compute; barrier] -- other blocks' MFMA
// streams hide this block's staging latency (TLP instead of double-buffer).
__global__ __launch_bounds__(256) void convk(const unsigned short* __restrict__ xT,
                                             const unsigned short* __restrict__ Wkb,
                                             const float* __restrict__ bk,
                                             const unsigned short* __restrict__ zp,
                                             unsigned short* __restrict__ kout) {
  __shared__ __align__(16) unsigned short Bs[2880 * 8];  // 46080 B
  // bijective XCD swizzle: 1024 blocks
  int orig = (blockIdx.x & 7) * 128 + (blockIdx.x >> 3);
  int g = orig & 31, b = (orig >> 5) & 7, h = orig >> 8;
  int d = 1 << h;
  int gpd = 32 >> h;
  int s = g / gpd;
  int q0 = (g - s * gpd) * 4;   // rows y = s + (q0+r)*d, r=0..3
  int nq = 128 >> h;
  int tid = threadIdx.x, lane = tid & 63, w = tid >> 6;  // w = col-quarter
  int l31 = lane & 31, hi = lane >> 5;
  const unsigned short* xb = xT + (size_t)b * 4194304;

  f32x16 acc[2][4];
#pragma unroll
  for (int i = 0; i < 2; i++)
#pragma unroll
    for (int j = 0; j < 4; j++)
#pragma unroll
      for (int r = 0; r < 16; r++) acc[i][j][r] = 0.f;

  // STAGE chunk c: items [0,1728) halo (slot*6+plane)*144+px ; [1728,2880) weights
  auto STAGE = [&](int c) {
#pragma unroll
    for (int it = 0; it < 12; it++) {
      int base = it * 256 + w * 64;   // wave-uniform; 2880 % 64 == 0
      if (base < 2880) {
        int p = base + lane;
        const unsigned short* gsrc;
        if (p < 1728) {               // wave-uniform split (1728 % 64 == 0)
          int px = p % 144;
          int sp = p / 144;
          int plane = sp % 6, slot = sp / 6;
          int q = q0 + plane - 1;
          int xc = px - d;
          bool ok = (q >= 0) & (q < nq) & (xc >= 0) & (xc < 128);
          gsrc = ok ? xb + (size_t)((s + q * d) * 128 + xc) * 256 + c * 16 + slot * 8
                    : zp;
        } else {
          int idx2 = p - 1728;        // (t*2+slot)*64 + pp
          int pp = idx2 & 63, ts = idx2 >> 6;
          int t = ts >> 1, slot = ts & 1;
          gsrc = Wkb + (size_t)(((h * 9 + t) * 32 + c * 2 + slot) * 64 + pp) * 8;
        }
        __builtin_amdgcn_global_load_lds(
            (const __attribute__((address_space(1))) void*)gsrc,
            (__attribute__((address_space(3))) void*)&Bs[(size_t)base * 8], 16, 0, 0);
      }
    }
  };

  STAGE(0);
#pragma unroll 1
  for (int c = 0; c < 16; c++) {
    asm volatile("s_waitcnt vmcnt(0)" ::: "memory");
    __builtin_amdgcn_s_barrier();
    __builtin_amdgcn_sched_barrier(0);
#pragma unroll
    for (int tx = 0; tx < 3; tx++) {
      f16x8 bfr[6];
#pragma unroll
      for (int p6 = 0; p6 < 6; p6++)
        bfr[p6] = *(const f16x8*)&Bs[((hi * 6 + p6) * 144 + w * 32 + d * tx + l31) * 8];
#pragma unroll
      for (int ty = 0; ty < 3; ty++) {
        int t = ty * 3 + tx;
        f16x8 a0 = *(const f16x8*)&Bs[(1728 + (t * 2 + hi) * 64 + l31) * 8];
        f16x8 a1 = *(const f16x8*)&Bs[(1728 + (t * 2 + hi) * 64 + 32 + l31) * 8];
#pragma unroll
        for (int r = 0; r < 4; r++) {
          acc[0][r] = mfma32(a0, bfr[r + ty], acc[0][r]);
          acc[1][r] = mfma32(a1, bfr[r + ty], acc[1][r]);
        }
      }
    }
    asm volatile("s_waitcnt lgkmcnt(0)" ::: "memory");
    __builtin_amdgcn_sched_barrier(0);
    __builtin_amdgcn_s_barrier();
    __builtin_amdgcn_sched_barrier(0);
    if (c < 15) STAGE(c + 1);
    __builtin_amdgcn_sched_barrier(0);
  }

  // epilogue: wave w owns cols w*32..w*32+31, rows r=0..3 (y = s+(q0+r)*d)
  unsigned short* kb = kout + (size_t)((h * 8 + b) * 64) * 16384;
#pragma unroll
  for (int mo = 0; mo < 2; mo++)
#pragma unroll
    for (int r = 0; r < 4; r++) {
      int y = s + (q0 + r) * d;
#pragma unroll
      for (int reg = 0; reg < 16; reg++) {
        int p = mo * 32 + (reg & 3) + 8 * (reg >> 2) + 4 * hi;
        int x = w * 32 + l31;
        kb[(size_t)p * 16384 + y * 128 + x] = f2h(acc[mo][r][reg] + bk[h * 64 + p]);
      }
    }
}

// ---------------- scores partials: q . k^T over n-chunk of 2048 ----------------
__global__ __launch_bounds__(256) void scoresk(const unsigned short* __restrict__ qin,
                                               const unsigned short* __restrict__ kin,
                                               float* __restrict__ part) {
  __shared__ __align__(16) unsigned short As[64 * 64];
  __shared__ __align__(16) unsigned short Bs[64 * 64];
  int nch = blockIdx.x, b = blockIdx.y, h = blockIdx.z;
  int tid = threadIdx.x, lane = tid & 63, w = tid >> 6;
  int l15 = lane & 15, uq = lane >> 4;
  const unsigned short* qb = qin + (size_t)((h * 8 + b) * 64) * 16384;
  const unsigned short* kb = kin + (size_t)((h * 8 + b) * 64) * 16384;
  int moff = (w >> 1) * 32, noff = (w & 1) * 32;
  const f32x4 fz = {0.f, 0.f, 0.f, 0.f};
  f32x4 acc[2][2] = {{fz, fz}, {fz, fz}};
  for (int ci = 0; ci < 32; ci++) {
    int nb = nch * 2048 + ci * 64;
    __syncthreads();
    for (int p = tid; p < 512; p += 256) {
      int row = p >> 3, j = p & 7;
      *(uint4*)&As[sw(row, j * 8)] = *(const uint4*)(qb + (size_t)row * 16384 + nb + j * 8);
      *(uint4*)&Bs[sw(row, j * 8)] = *(const uint4*)(kb + (size_t)row * 16384 + nb + j * 8);
    }
    __syncthreads();
#pragma unroll
    for (int kk = 0; kk < 2; kk++) {
      f16x8 b0 = *(const f16x8*)&Bs[sw(noff + l15, kk * 32 + uq * 8)];
      f16x8 b1 = *(const f16x8*)&Bs[sw(noff + 16 + l15, kk * 32 + uq * 8)];
      f16x8 a0 = *(const f16x8*)&As[sw(moff + l15, kk * 32 + uq * 8)];
      f16x8 a1 = *(const f16x8*)&As[sw(moff + 16 + l15, kk * 32 + uq * 8)];
      acc[0][0] = mfma16(a0, b0, acc[0][0]);
      acc[0][1] = mfma16(a0, b1, acc[0][1]);
      acc[1][0] = mfma16(a1, b0, acc[1][0]);
      acc[1][1] = mfma16(a1, b1, acc[1][1]);
    }
  }
  float* pb = part + (size_t)((nch * 4 + h) * 8 + b) * 4096;
#pragma unroll
  for (int mf = 0; mf < 2; mf++)
#pragma unroll
    for (int nf = 0; nf < 2; nf++) {
      int p = noff + nf * 16 + l15;
#pragma unroll
      for (int r = 0; r < 4; r++) {
        int o = moff + mf * 16 + 4 * uq + r;
        pb[o * 64 + p] = acc[mf][nf][r];
      }
    }
}

// ---------------- softmax over p (one wave per (h,b,o) row) ----------------
__global__ __launch_bounds__(256) void smax(const float* __restrict__ part,
                                            unsigned short* __restrict__ attn) {
  int row = blockIdx.x * 4 + (threadIdx.x >> 6);
  int lane = threadIdx.x & 63;
  int h = row >> 9, b = (row >> 6) & 7, o = row & 63;
  float s = 0.f;
#pragma unroll
  for (int nch = 0; nch < 8; nch++)
    s += part[(size_t)((nch * 4 + h) * 8 + b) * 4096 + o * 64 + lane];
  s *= 0.0625f;  // 1/sqrt(256)
  float m = s;
#pragma unroll
  for (int k = 32; k > 0; k >>= 1) m = fmaxf(m, __shfl_xor(m, k, 64));
  float e = __expf(s - m);
  float sum = e;
#pragma unroll
  for (int k = 32; k > 0; k >>= 1) sum += __shfl_xor(sum, k, 64);
  attn[(size_t)(h * 8 + b) * 4096 + o * 64 + lane] = f2h(e / sum);
}

// ---------------- out = attn @ v ----------------
__global__ __launch_bounds__(256) void outk(const unsigned short* __restrict__ attn,
                                            const unsigned short* __restrict__ vT,
                                            float* __restrict__ out) {
  __shared__ __align__(16) unsigned short As[64 * 64];
  __shared__ __align__(16) unsigned short Bs[256 * 64];
  int n0 = blockIdx.x * 256, b = blockIdx.y, h = blockIdx.z;
  int tid = threadIdx.x, lane = tid & 63, w = tid >> 6;
  int l15 = lane & 15, uq = lane >> 4;
  const unsigned short* ab = attn + (size_t)(h * 8 + b) * 4096;
  const unsigned short* vb = vT + (size_t)(h * 8 + b) * 16384 * 64;
  for (int p = tid; p < 512; p += 256) {
    int row = p >> 3, j = p & 7;
    *(uint4*)&As[sw(row, j * 8)] = *(const uint4*)(ab + row * 64 + j * 8);
  }
  for (int p = tid; p < 2048; p += 256) {
    int px = p >> 3, j = p & 7;
    *(uint4*)&Bs[sw(px, j * 8)] = *(const uint4*)(vb + (size_t)(n0 + px) * 64 + j * 8);
  }
  __syncthreads();
  const f32x4 fz = {0.f, 0.f, 0.f, 0.f};
  f32x4 acc[4][4];
#pragma unroll
  for (int i = 0; i < 4; i++)
#pragma unroll
    for (int j = 0; j < 4; j++) acc[i][j] = fz;
#pragma unroll
  for (int kk = 0; kk < 2; kk++) {
    f16x8 bfr[4];
#pragma unroll
    for (int nf = 0; nf < 4; nf++)
      bfr[nf] = *(const f16x8*)&Bs[sw(w * 64 + nf * 16 + l15, kk * 32 + uq * 8)];
#pragma unroll
    for (int mf = 0; mf < 4; mf++) {
      f16x8 afr = *(const f16x8*)&As[sw(mf * 16 + l15, kk * 32 + uq * 8)];
#pragma unroll
      for (int nf = 0; nf < 4; nf++) acc[mf][nf] = mfma16(afr, bfr[nf], acc[mf][nf]);
    }
  }
  float* ob = out + (size_t)b * 4194304 + (size_t)(h * 64) * 16384;
#pragma unroll
  for (int mf = 0; mf < 4; mf++)
#pragma unroll
    for (int nf = 0; nf < 4; nf++) {
      int n = n0 + w * 64 + nf * 16 + l15;
#pragma unroll
      for (int r = 0; r < 4; r++) {
        int o = mf * 16 + 4 * uq + r;
        ob[(size_t)o * 16384 + n] = acc[mf][nf][r];
      }
    }
}

extern "C" void kernel_launch(void* const* d_in, const int* in_sizes, int n_in,
                              void* d_out, int out_size, void* d_ws, size_t ws_size,
                              hipStream_t stream) {
  const float* x  = (const float*)d_in[0];
  const float* Wq = (const float*)d_in[1];
  const float* bq = (const float*)d_in[2];
  const float* Wk = (const float*)d_in[3];
  const float* bk = (const float*)d_in[4];
  const float* Wv = (const float*)d_in[5];
  const float* bv = (const float*)d_in[6];
  float* out = (float*)d_out;

  char* ws = (char*)d_ws;
  unsigned short* kbuf = (unsigned short*)(ws);
  unsigned short* vT   = (unsigned short*)(ws + 67108864);
  unsigned short* attn = (unsigned short*)(ws + 134217728);
  unsigned short* Wqv  = (unsigned short*)(ws + 134479872);
  unsigned short* Wkb  = (unsigned short*)(ws + 134742016);
  unsigned short* zp   = (unsigned short*)(ws + 135921664);
  // d_out doubles as scratch: xT in first half, q in second; part reuses dead xT.
  unsigned short* xT = (unsigned short*)d_out;
  unsigned short* qb = (unsigned short*)d_out + 33554432;
  float* part = (float*)d_out;

  prep<<<dim3(2816), dim3(256), 0, stream>>>(Wq, Wv, Wk, Wqv, Wkb, zp);
  xpose<<<dim3(256, 4, 8), dim3(256), 0, stream>>>(x, xT);
  proj<<<dim3(64, 4, 8), dim3(256), 0, stream>>>(xT, Wqv, bq, bv, qb, vT);
  convk<<<dim3(1024), dim3(256), 0, stream>>>(xT, Wkb, bk, zp, kbuf);
  scoresk<<<dim3(8, 8, 4), dim3(256), 0, stream>>>(qb, kbuf, part);
  smax<<<dim3(512), dim3(256), 0, stream>>>(part, attn);
  outk<<<dim3(64, 8, 4), dim3(256), 0, stream>>>(attn, vT, out);
}

// Round 9
// 429.117 us; speedup vs baseline: 1.0645x; 1.0645x over previous
//
#include <hip/hip_runtime.h>
#include <hip/hip_bf16.h>

// Channel attention (4 heads, dilated 3x3 key convs d=1,2,4,8), f16 MFMA pipeline.
// R9: convk register diet -- launch_bounds(256,2), staging pointers precomputed
// once + self-incremented (no in-loop address math) -> 2 waves/SIMD co-residency.
//
// ws layout (bytes):
//   kbuf : [0,           67108864)   k  f16 [h][b][p][n]
//   vT   : [67108864,   134217728)   v  f16 [h][b][n][p]   (pixel-major)
//   attn : [134217728,  134479872)   attn f16 [h][b][o][p]
//   Wqv  : [134479872,  134742016)   f16 (512x256)
//   Wkb  : [134742016,  135921664)   f16 [h][t][ks32][p64][8]  (MFMA A-frag native)
//   zpage: [135921664,  135922176)   zeros (OOB load source, 512 B)
// d_out reused as scratch (dead before final kernel):
//   xT   : bytes [0, 64Mi)   f16 [b][n][c]
//   q    : bytes [64Mi,128Mi) f16 [h][b][o][n]
//   part : bytes [0, 4Mi)    fp32 partial scores (written AFTER conv, xT dead)

typedef __attribute__((ext_vector_type(8))) _Float16 f16x8;
typedef __attribute__((ext_vector_type(4))) float f32x4;
typedef __attribute__((ext_vector_type(16))) float f32x16;

__device__ __forceinline__ unsigned short f2h(float f) {
  union { _Float16 h; unsigned short u; } v;
  v.h = (_Float16)f;
  return v.u;
}

__device__ __forceinline__ f32x4 mfma16(f16x8 a, f16x8 b, f32x4 c) {
  return __builtin_amdgcn_mfma_f32_16x16x32_f16(a, b, c, 0, 0, 0);
}
__device__ __forceinline__ f32x16 mfma32(f16x8 a, f16x8 b, f32x16 c) {
  return __builtin_amdgcn_mfma_f32_32x32x16_f16(a, b, c, 0, 0, 0);
}

// swizzled index into a [R][64]-ushort tile (128B rows): XOR bits 4..6 of byte off
__device__ __forceinline__ int sw(int row, int c) {
  return row * 64 + ((((c << 1) ^ ((row & 7) << 4)) >> 1));
}

// ---------------- weight prep ----------------
__global__ __launch_bounds__(256) void prep(const float* __restrict__ Wq,
                                            const float* __restrict__ Wv,
                                            const float* __restrict__ Wk,
                                            unsigned short* __restrict__ Wqv,
                                            unsigned short* __restrict__ Wkb,
                                            unsigned short* __restrict__ zp) {
  int i = blockIdx.x * 256 + threadIdx.x;
  if (blockIdx.x == 0) zp[threadIdx.x] = 0;  // 512 B zero page
  const int total = 131072 + 589824;
  if (i >= total) return;
  if (i < 131072) {
    Wqv[i] = f2h(i < 65536 ? Wq[i] : Wv[i - 65536]);
  } else {
    int j = i - 131072;  // (((h*9+t)*32 + ks)*64 + p)*8 + jj
    int jj = j & 7;
    int p = (j >> 3) & 63;
    int ks = (j >> 9) & 31;
    int ht = j >> 14;
    int t = ht % 9;
    int h = ht / 9;
    Wkb[j] = f2h(Wk[(size_t)((h * 64 + p) * 256 + ks * 8 + jj) * 9 + t]);
  }
}

// ---------------- x (b,c,n) fp32 -> xT (b,n,c) f16 ----------------
__global__ __launch_bounds__(256) void xpose(const float* __restrict__ x,
                                             unsigned short* __restrict__ xT) {
  __shared__ unsigned short tile[64][66];
  int n0 = blockIdx.x * 64, c0 = blockIdx.y * 64, b = blockIdx.z;
  int t = threadIdx.x;
  int r = t >> 2, q = t & 3;
  const float* src = x + (size_t)b * 4194304 + (size_t)(c0 + r) * 16384 + n0 + q * 16;
#pragma unroll
  for (int i = 0; i < 4; i++) {
    float4 v = *(const float4*)(src + i * 4);
    tile[r][q * 16 + i * 4 + 0] = f2h(v.x);
    tile[r][q * 16 + i * 4 + 1] = f2h(v.y);
    tile[r][q * 16 + i * 4 + 2] = f2h(v.z);
    tile[r][q * 16 + i * 4 + 3] = f2h(v.w);
  }
  __syncthreads();
  int c = t & 63, pq = t >> 6;
  unsigned short* dst = xT + (size_t)b * 4194304 + (size_t)n0 * 256 + c0 + c;
#pragma unroll
  for (int i = 0; i < 16; i++) {
    int px = i * 4 + pq;
    dst[(size_t)px * 256] = tile[c][px];
  }
}

// ---------------- Q/V projection: q-tile + v-tile paired, shared x staging -----
__global__ __launch_bounds__(256) void proj(const unsigned short* __restrict__ xT,
                                            const unsigned short* __restrict__ Wqv,
                                            const float* __restrict__ bq,
                                            const float* __restrict__ bv,
                                            unsigned short* __restrict__ qout,
                                            unsigned short* __restrict__ vT) {
  __shared__ __align__(16) unsigned short As[2][64 * 64];
  __shared__ __align__(16) unsigned short Bs[256 * 64];
  int n0 = blockIdx.x * 256, y = blockIdx.y, b = blockIdx.z;
  int h = y;  // head
  int tid = threadIdx.x, lane = tid & 63, w = tid >> 6;
  int l15 = lane & 15, uq = lane >> 4;
  const f32x4 fz = {0.f, 0.f, 0.f, 0.f};
  f32x4 acc[2][4][4];
#pragma unroll
  for (int m = 0; m < 2; m++)
#pragma unroll
    for (int i = 0; i < 4; i++)
#pragma unroll
      for (int j = 0; j < 4; j++) acc[m][i][j] = fz;

  const unsigned short* xb = xT + (size_t)b * 4194304;
  for (int k0 = 0; k0 < 256; k0 += 64) {
    __syncthreads();
    for (int p = tid; p < 1024; p += 256) {
      int sel = p >> 9, row = (p >> 3) & 63, j = p & 7;
      int m0 = sel * 256 + y * 64;
      uint4 v = *(const uint4*)(Wqv + (size_t)(m0 + row) * 256 + k0 + j * 8);
      *(uint4*)&As[sel][sw(row, j * 8)] = v;
    }
    for (int p = tid; p < 2048; p += 256) {
      int px = p >> 3, j = p & 7;
      uint4 v = *(const uint4*)(xb + (size_t)(n0 + px) * 256 + k0 + j * 8);
      *(uint4*)&Bs[sw(px, j * 8)] = v;
    }
    __syncthreads();
#pragma unroll
    for (int kk = 0; kk < 2; kk++) {
      f16x8 bfr[4];
#pragma unroll
      for (int nf = 0; nf < 4; nf++)
        bfr[nf] = *(const f16x8*)&Bs[sw(w * 64 + nf * 16 + l15, kk * 32 + uq * 8)];
#pragma unroll
      for (int mh = 0; mh < 2; mh++)
#pragma unroll
        for (int mf = 0; mf < 4; mf++) {
          f16x8 afr = *(const f16x8*)&As[mh][sw(mf * 16 + l15, kk * 32 + uq * 8)];
#pragma unroll
          for (int nf = 0; nf < 4; nf++)
            acc[mh][mf][nf] = mfma16(afr, bfr[nf], acc[mh][mf][nf]);
        }
    }
  }
  // q path (mh=0)
  {
    unsigned short* qb = qout + (size_t)((h * 8 + b) * 64) * 16384;
#pragma unroll
    for (int mf = 0; mf < 4; mf++)
#pragma unroll
      for (int nf = 0; nf < 4; nf++) {
        int n = n0 + w * 64 + nf * 16 + l15;
#pragma unroll
        for (int r = 0; r < 4; r++) {
          int o = mf * 16 + 4 * uq + r;
          qb[(size_t)o * 16384 + n] = f2h(acc[0][mf][nf][r] + bq[h * 64 + o]);
        }
      }
  }
  // v path (mh=1)
  {
    unsigned short* vb = vT + (size_t)(h * 8 + b) * 16384 * 64;
#pragma unroll
    for (int mf = 0; mf < 4; mf++) {
      int p0 = mf * 16 + 4 * uq;
#pragma unroll
      for (int nf = 0; nf < 4; nf++) {
        int n = n0 + w * 64 + nf * 16 + l15;
        unsigned short t0 = f2h(acc[1][mf][nf][0] + bv[h * 64 + p0 + 0]);
        unsigned short t1 = f2h(acc[1][mf][nf][1] + bv[h * 64 + p0 + 1]);
        unsigned short t2 = f2h(acc[1][mf][nf][2] + bv[h * 64 + p0 + 2]);
        unsigned short t3 = f2h(acc[1][mf][nf][3] + bv[h * 64 + p0 + 3]);
        uint2 pk;
        pk.x = (unsigned)t0 | ((unsigned)t1 << 16);
        pk.y = (unsigned)t2 | ((unsigned)t3 << 16);
        *(uint2*)&vb[(size_t)n * 64 + p0] = pk;
      }
    }
  }
}

// ---------------- dilated 3x3 conv (keys): 4 d-spaced rows, all-LDS operands ---
// launch_bounds(256,2): cap total regs at 256 (128 AGPR acc + <=128 VGPR) so
// 2 blocks/CU co-reside; staging pointers precomputed + self-incremented.
__global__ __launch_bounds__(256, 2) void convk(const unsigned short* __restrict__ xT,
                                                const unsigned short* __restrict__ Wkb,
                                                const float* __restrict__ bk,
                                                const unsigned short* __restrict__ zp,
                                                unsigned short* __restrict__ kout) {
  __shared__ __align__(16) unsigned short Bs[2880 * 8];  // 46080 B
  // bijective XCD swizzle: 1024 blocks
  int orig = (blockIdx.x & 7) * 128 + (blockIdx.x >> 3);
  int g = orig & 31, b = (orig >> 5) & 7, h = orig >> 8;
  int d = 1 << h;
  int gpd = 32 >> h;
  int s = g / gpd;
  int q0 = (g - s * gpd) * 4;   // rows y = s + (q0+r)*d, r=0..3
  int nq = 128 >> h;
  int tid = threadIdx.x, lane = tid & 63, w = tid >> 6;  // w = col-quarter
  int l31 = lane & 31, hi = lane >> 5;
  const unsigned short* xb = xT + (size_t)b * 4194304;

  f32x16 acc[2][4];
#pragma unroll
  for (int i = 0; i < 2; i++)
#pragma unroll
    for (int j = 0; j < 4; j++)
#pragma unroll
      for (int r = 0; r < 16; r++) acc[i][j][r] = 0.f;

  // ---- precompute staging pointers (chunk 0) + per-lane byte strides.
  // items [0,1728): halo (slot*6+plane)*144+px ; [1728,2880): weights.
  const char* aptr[12];
  int astr[12];
#pragma unroll
  for (int it = 0; it < 12; it++) {
    int base = it * 256 + w * 64;   // wave-uniform; guard below wave-uniform too
    aptr[it] = (const char*)zp;
    astr[it] = 0;
    if (base < 2880) {
      int p = base + lane;
      if (p < 1728) {               // 1728 % 64 == 0 -> wave-uniform split
        int px = p % 144;
        int sp = p / 144;
        int plane = sp % 6, slot = sp / 6;
        int q = q0 + plane - 1;
        int xc = px - d;
        bool ok = (q >= 0) & (q < nq) & (xc >= 0) & (xc < 128);
        aptr[it] = (const char*)(ok ? xb + (size_t)((s + q * d) * 128 + xc) * 256 + slot * 8
                                    : zp);
        astr[it] = 32;              // c*16 f16 elements per chunk
      } else {
        int idx2 = p - 1728;        // (t*2+slot)*64 + pp
        int pp = idx2 & 63, ts = idx2 >> 6;
        int t = ts >> 1, slot = ts & 1;
        aptr[it] = (const char*)(Wkb + (size_t)(((h * 9 + t) * 32 + slot) * 64 + pp) * 8);
        astr[it] = 2048;            // c*2 kslots of 64x8 f16 per chunk
      }
    }
  }

  auto STAGE = [&]() {
#pragma unroll
    for (int it = 0; it < 12; it++) {
      int base = it * 256 + w * 64;
      if (base < 2880) {
        __builtin_amdgcn_global_load_lds(
            (const __attribute__((address_space(1))) void*)aptr[it],
            (__attribute__((address_space(3))) void*)&Bs[(size_t)base * 8], 16, 0, 0);
        aptr[it] += astr[it];
      }
    }
  };

  STAGE();
#pragma unroll 1
  for (int c = 0; c < 16; c++) {
    asm volatile("s_waitcnt vmcnt(0)" ::: "memory");
    __builtin_amdgcn_s_barrier();
    __builtin_amdgcn_sched_barrier(0);
    __builtin_amdgcn_s_setprio(1);
#pragma unroll
    for (int tx = 0; tx < 3; tx++) {
      f16x8 bfr[6];
#pragma unroll
      for (int p6 = 0; p6 < 6; p6++)
        bfr[p6] = *(const f16x8*)&Bs[((hi * 6 + p6) * 144 + w * 32 + d * tx + l31) * 8];
#pragma unroll
      for (int ty = 0; ty < 3; ty++) {
        int t = ty * 3 + tx;
        f16x8 a0 = *(const f16x8*)&Bs[(1728 + (t * 2 + hi) * 64 + l31) * 8];
        f16x8 a1 = *(const f16x8*)&Bs[(1728 + (t * 2 + hi) * 64 + 32 + l31) * 8];
#pragma unroll
        for (int r = 0; r < 4; r++) {
          acc[0][r] = mfma32(a0, bfr[r + ty], acc[0][r]);
          acc[1][r] = mfma32(a1, bfr[r + ty], acc[1][r]);
        }
      }
    }
    __builtin_amdgcn_s_setprio(0);
    asm volatile("s_waitcnt lgkmcnt(0)" ::: "memory");
    __builtin_amdgcn_sched_barrier(0);
    __builtin_amdgcn_s_barrier();
    __builtin_amdgcn_sched_barrier(0);
    if (c < 15) STAGE();
    __builtin_amdgcn_sched_barrier(0);
  }

  // epilogue: wave w owns cols w*32..w*32+31, rows r=0..3 (y = s+(q0+r)*d)
  unsigned short* kb = kout + (size_t)((h * 8 + b) * 64) * 16384;
#pragma unroll
  for (int mo = 0; mo < 2; mo++)
#pragma unroll
    for (int r = 0; r < 4; r++) {
      int y = s + (q0 + r) * d;
#pragma unroll
      for (int reg = 0; reg < 16; reg++) {
        int p = mo * 32 + (reg & 3) + 8 * (reg >> 2) + 4 * hi;
        int x = w * 32 + l31;
        kb[(size_t)p * 16384 + y * 128 + x] = f2h(acc[mo][r][reg] + bk[h * 64 + p]);
      }
    }
}

// ---------------- scores partials: q . k^T over n-chunk of 2048 ----------------
__global__ __launch_bounds__(256) void scoresk(const unsigned short* __restrict__ qin,
                                               const unsigned short* __restrict__ kin,
                                               float* __restrict__ part) {
  __shared__ __align__(16) unsigned short As[64 * 64];
  __shared__ __align__(16) unsigned short Bs[64 * 64];
  int nch = blockIdx.x, b = blockIdx.y, h = blockIdx.z;
  int tid = threadIdx.x, lane = tid & 63, w = tid >> 6;
  int l15 = lane & 15, uq = lane >> 4;
  const unsigned short* qb = qin + (size_t)((h * 8 + b) * 64) * 16384;
  const unsigned short* kb = kin + (size_t)((h * 8 + b) * 64) * 16384;
  int moff = (w >> 1) * 32, noff = (w & 1) * 32;
  const f32x4 fz = {0.f, 0.f, 0.f, 0.f};
  f32x4 acc[2][2] = {{fz, fz}, {fz, fz}};
  for (int ci = 0; ci < 32; ci++) {
    int nb = nch * 2048 + ci * 64;
    __syncthreads();
    for (int p = tid; p < 512; p += 256) {
      int row = p >> 3, j = p & 7;
      *(uint4*)&As[sw(row, j * 8)] = *(const uint4*)(qb + (size_t)row * 16384 + nb + j * 8);
      *(uint4*)&Bs[sw(row, j * 8)] = *(const uint4*)(kb + (size_t)row * 16384 + nb + j * 8);
    }
    __syncthreads();
#pragma unroll
    for (int kk = 0; kk < 2; kk++) {
      f16x8 b0 = *(const f16x8*)&Bs[sw(noff + l15, kk * 32 + uq * 8)];
      f16x8 b1 = *(const f16x8*)&Bs[sw(noff + 16 + l15, kk * 32 + uq * 8)];
      f16x8 a0 = *(const f16x8*)&As[sw(moff + l15, kk * 32 + uq * 8)];
      f16x8 a1 = *(const f16x8*)&As[sw(moff + 16 + l15, kk * 32 + uq * 8)];
      acc[0][0] = mfma16(a0, b0, acc[0][0]);
      acc[0][1] = mfma16(a0, b1, acc[0][1]);
      acc[1][0] = mfma16(a1, b0, acc[1][0]);
      acc[1][1] = mfma16(a1, b1, acc[1][1]);
    }
  }
  float* pb = part + (size_t)((nch * 4 + h) * 8 + b) * 4096;
#pragma unroll
  for (int mf = 0; mf < 2; mf++)
#pragma unroll
    for (int nf = 0; nf < 2; nf++) {
      int p = noff + nf * 16 + l15;
#pragma unroll
      for (int r = 0; r < 4; r++) {
        int o = moff + mf * 16 + 4 * uq + r;
        pb[o * 64 + p] = acc[mf][nf][r];
      }
    }
}

// ---------------- softmax over p (one wave per (h,b,o) row) ----------------
__global__ __launch_bounds__(256) void smax(const float* __restrict__ part,
                                            unsigned short* __restrict__ attn) {
  int row = blockIdx.x * 4 + (threadIdx.x >> 6);
  int lane = threadIdx.x & 63;
  int h = row >> 9, b = (row >> 6) & 7, o = row & 63;
  float s = 0.f;
#pragma unroll
  for (int nch = 0; nch < 8; nch++)
    s += part[(size_t)((nch * 4 + h) * 8 + b) * 4096 + o * 64 + lane];
  s *= 0.0625f;  // 1/sqrt(256)
  float m = s;
#pragma unroll
  for (int k = 32; k > 0; k >>= 1) m = fmaxf(m, __shfl_xor(m, k, 64));
  float e = __expf(s - m);
  float sum = e;
#pragma unroll
  for (int k = 32; k > 0; k >>= 1) sum += __shfl_xor(sum, k, 64);
  attn[(size_t)(h * 8 + b) * 4096 + o * 64 + lane] = f2h(e / sum);
}

// ---------------- out = attn @ v ----------------
__global__ __launch_bounds__(256) void outk(const unsigned short* __restrict__ attn,
                                            const unsigned short* __restrict__ vT,
                                            float* __restrict__ out) {
  __shared__ __align__(16) unsigned short As[64 * 64];
  __shared__ __align__(16) unsigned short Bs[256 * 64];
  int n0 = blockIdx.x * 256, b = blockIdx.y, h = blockIdx.z;
  int tid = threadIdx.x, lane = tid & 63, w = tid >> 6;
  int l15 = lane & 15, uq = lane >> 4;
  const unsigned short* ab = attn + (size_t)(h * 8 + b) * 4096;
  const unsigned short* vb = vT + (size_t)(h * 8 + b) * 16384 * 64;
  for (int p = tid; p < 512; p += 256) {
    int row = p >> 3, j = p & 7;
    *(uint4*)&As[sw(row, j * 8)] = *(const uint4*)(ab + row * 64 + j * 8);
  }
  for (int p = tid; p < 2048; p += 256) {
    int px = p >> 3, j = p & 7;
    *(uint4*)&Bs[sw(px, j * 8)] = *(const uint4*)(vb + (size_t)(n0 + px) * 64 + j * 8);
  }
  __syncthreads();
  const f32x4 fz = {0.f, 0.f, 0.f, 0.f};
  f32x4 acc[4][4];
#pragma unroll
  for (int i = 0; i < 4; i++)
#pragma unroll
    for (int j = 0; j < 4; j++) acc[i][j] = fz;
#pragma unroll
  for (int kk = 0; kk < 2; kk++) {
    f16x8 bfr[4];
#pragma unroll
    for (int nf = 0; nf < 4; nf++)
      bfr[nf] = *(const f16x8*)&Bs[sw(w * 64 + nf * 16 + l15, kk * 32 + uq * 8)];
#pragma unroll
    for (int mf = 0; mf < 4; mf++) {
      f16x8 afr = *(const f16x8*)&As[sw(mf * 16 + l15, kk * 32 + uq * 8)];
#pragma unroll
      for (int nf = 0; nf < 4; nf++) acc[mf][nf] = mfma16(afr, bfr[nf], acc[mf][nf]);
    }
  }
  float* ob = out + (size_t)b * 4194304 + (size_t)(h * 64) * 16384;
#pragma unroll
  for (int mf = 0; mf < 4; mf++)
#pragma unroll
    for (int nf = 0; nf < 4; nf++) {
      int n = n0 + w * 64 + nf * 16 + l15;
#pragma unroll
      for (int r = 0; r < 4; r++) {
        int o = mf * 16 + 4 * uq + r;
        ob[(size_t)o * 16384 + n] = acc[mf][nf][r];
      }
    }
}

extern "C" void kernel_launch(void* const* d_in, const int* in_sizes, int n_in,
                              void* d_out, int out_size, void* d_ws, size_t ws_size,
                              hipStream_t stream) {
  const float* x  = (const float*)d_in[0];
  const float* Wq = (const float*)d_in[1];
  const float* bq = (const float*)d_in[2];
  const float* Wk = (const float*)d_in[3];
  const float* bk = (const float*)d_in[4];
  const float* Wv = (const float*)d_in[5];
  const float* bv = (const float*)d_in[6];
  float* out = (float*)d_out;

  char* ws = (char*)d_ws;
  unsigned short* kbuf = (unsigned short*)(ws);
  unsigned short* vT   = (unsigned short*)(ws + 67108864);
  unsigned short* attn = (unsigned short*)(ws + 134217728);
  unsigned short* Wqv  = (unsigned short*)(ws + 134479872);
  unsigned short* Wkb  = (unsigned short*)(ws + 134742016);
  unsigned short* zp   = (unsigned short*)(ws + 135921664);
  // d_out doubles as scratch: xT in first half, q in second; part reuses dead xT.
  unsigned short* xT = (unsigned short*)d_out;
  unsigned short* qb = (unsigned short*)d_out + 33554432;
  float* part = (float*)d_out;

  prep<<<dim3(2816), dim3(256), 0, stream>>>(Wq, Wv, Wk, Wqv, Wkb, zp);
  xpose<<<dim3(256, 4, 8), dim3(256), 0, stream>>>(x, xT);
  proj<<<dim3(64, 4, 8), dim3(256), 0, stream>>>(xT, Wqv, bq, bv, qb, vT);
  convk<<<dim3(1024), dim3(256), 0, stream>>>(xT, Wkb, bk, zp, kbuf);
  scoresk<<<dim3(8, 8, 4), dim3(256), 0, stream>>>(qb, kbuf, part);
  smax<<<dim3(512), dim3(256), 0, stream>>>(part, attn);
  outk<<<dim3(64, 8, 4), dim3(256), 0, stream>>>(attn, vT, out);
}